// Round 5
// baseline (2218.129 us; speedup 1.0000x reference)
//
#include <hip/hip_runtime.h>
#include <math.h>
#include <stdint.h>

#define DIMM 512
#define MATF ((size_t)DIMM * DIMM)       // 262144
#define PLANE 262144                     // hi -> lo plane offset (ushorts)
#define SLOT_USH (2 * 262144)            // pair slot per batch (ushorts) = 1 MiB

typedef __attribute__((ext_vector_type(8))) short short8v;
typedef __attribute__((ext_vector_type(8))) unsigned short ushort8v;
typedef __attribute__((ext_vector_type(4))) float f32x4;

__device__ __forceinline__ unsigned short bf16_rne(float f) {
    unsigned u = __builtin_bit_cast(unsigned, f);
    u += 0x7FFFu + ((u >> 16) & 1u);
    return (unsigned short)(u >> 16);
}
__device__ __forceinline__ float bf16_to_f(unsigned short h) {
    unsigned u = ((unsigned)h) << 16;
    return __builtin_bit_cast(float, u);
}
__device__ __forceinline__ float sgn_sqrt(float tv)
{
    float r = sqrtf(fabsf(tv) + 1e-5f);
    return tv > 0.f ? r : (tv < 0.f ? -r : 0.f);
}

// mode bits for ns_multi slices
#define MODE_SA  1   // scale staged A by 1/norm (pair re-round)
#define MODE_SB  2   // scale staged B by 1/norm
#define MODE_SPV 4   // scale epilogue A-read by 1/norm
#define MODE_SQ  8   // epilogue: v = sgn_sqrt(v * sqrt(norm))

struct NsArgs {
    const unsigned short* A[3];
    const unsigned short* B[3];
    unsigned short*       C[3];
    int mode[3];
    int gb0[3];
    int cnt[3];      // blocks per slice (= nb * 10)
};

__device__ __forceinline__ void scale_pair8(ushort8v& h0, ushort8v& h1,
                                            ushort8v& l0, ushort8v& l1, float rn)
{
#pragma unroll
    for (int j = 0; j < 8; ++j) {
        float v = (bf16_to_f(h0[j]) + bf16_to_f(l0[j])) * rn;
        unsigned short hh = bf16_rne(v);
        h0[j] = hh; l0[j] = bf16_rne(v - bf16_to_f(hh));
        float w = (bf16_to_f(h1[j]) + bf16_to_f(l1[j])) * rn;
        unsigned short wh = bf16_rne(w);
        h1[j] = wh; l1[j] = bf16_rne(w - bf16_to_f(wh));
    }
}

// ---------------------------------------------------------------------------
// Multi-slice NS GEMM: up to 3 independent slices per launch (pipelined
// batch-groups). Each slice: C_pair = f(1.5*A - 0.5*(A @ B^T-as-cols)),
// symmetric 10-tile + LDS-transpose mirror. XCD-aware remap. K=512 fixed.
// ---------------------------------------------------------------------------
__global__ __launch_bounds__(256, 4) void ns_multi(NsArgs args, const float* __restrict__ norm)
{
    __shared__ unsigned short sm[4 * 128 * 40];   // 40 KB; reused for transpose
    const int SM_AH = 0, SM_AL = 5120, SM_BH = 10240, SM_BL = 15360;

    const int nwg = gridDim.x;
    const int chunk = nwg >> 3;                   // nwg % 8 == 0
    int wu = (blockIdx.x & 7) * chunk + (blockIdx.x >> 3);

    // slice select (constant indices only)
    const unsigned short *Ab, *Bb; unsigned short* Cb; int mode, gb0;
    if (wu < args.cnt[0]) {
        Ab = args.A[0]; Bb = args.B[0]; Cb = args.C[0]; mode = args.mode[0]; gb0 = args.gb0[0];
    } else {
        wu -= args.cnt[0];
        if (wu < args.cnt[1]) {
            Ab = args.A[1]; Bb = args.B[1]; Cb = args.C[1]; mode = args.mode[1]; gb0 = args.gb0[1];
        } else {
            wu -= args.cnt[1];
            Ab = args.A[2]; Bb = args.B[2]; Cb = args.C[2]; mode = args.mode[2]; gb0 = args.gb0[2];
        }
    }

    const int lb = wu / 10;
    const int tile = wu - lb * 10;
    int ti, tj;
    if (tile < 4)      { ti = 0; tj = tile; }
    else if (tile < 7) { ti = 1; tj = tile - 3; }
    else if (tile < 9) { ti = 2; tj = tile - 5; }
    else               { ti = 3; tj = 3; }

    const unsigned short* A  = Ab + (size_t)lb * SLOT_USH;
    const unsigned short* Bp = Bb + (size_t)lb * SLOT_USH;
    unsigned short* C = Cb + (size_t)lb * SLOT_USH;

    float rn = 1.0f, sq = 0.0f;
    if (mode) {
        float nv = norm[gb0 + lb];
        rn = 1.0f / nv;
        sq = sqrtf(nv);
    }

    const int m0 = ti * 128;
    const int n0 = tj * 128;

    const int t = threadIdx.x;
    const int l = t & 63;
    const int w = t >> 6;
    const int wr = w >> 1, wc = w & 1;
    const int lr = l & 15, lc16 = (l >> 4) * 8;

    const int sr = t >> 1, sh = t & 1;
    const unsigned short* pA = A  + (size_t)(m0 + sr) * 512 + sh * 16;
    const unsigned short* pB = Bp + (size_t)(n0 + sr) * 512 + sh * 16;
    unsigned short* dAh = &sm[SM_AH + sr * 40 + sh * 16];
    unsigned short* dAl = &sm[SM_AL + sr * 40 + sh * 16];
    unsigned short* dBh = &sm[SM_BH + sr * 40 + sh * 16];
    unsigned short* dBl = &sm[SM_BL + sr * 40 + sh * 16];

    f32x4 acc[4][4] = {};

    ushort8v a0, a1, a2, a3, b0, b1, b2, b3;
#define LOADALL(OFF) do { \
    a0 = *(const ushort8v*)(pA + (OFF));          a1 = *(const ushort8v*)(pA + (OFF) + 8); \
    a2 = *(const ushort8v*)(pA + PLANE + (OFF));  a3 = *(const ushort8v*)(pA + PLANE + (OFF) + 8); \
    b0 = *(const ushort8v*)(pB + (OFF));          b1 = *(const ushort8v*)(pB + (OFF) + 8); \
    b2 = *(const ushort8v*)(pB + PLANE + (OFF));  b3 = *(const ushort8v*)(pB + PLANE + (OFF) + 8); \
  } while (0)

    LOADALL(0);
    for (int s = 0; s < 16; ++s) {
        __syncthreads();
        if (mode & MODE_SA) scale_pair8(a0, a1, a2, a3, rn);
        if (mode & MODE_SB) scale_pair8(b0, b1, b2, b3, rn);
        *(ushort8v*)(dAh) = a0; *(ushort8v*)(dAh + 8) = a1;
        *(ushort8v*)(dAl) = a2; *(ushort8v*)(dAl + 8) = a3;
        *(ushort8v*)(dBh) = b0; *(ushort8v*)(dBh + 8) = b1;
        *(ushort8v*)(dBl) = b2; *(ushort8v*)(dBl + 8) = b3;
        __syncthreads();
        if (s + 1 < 16) LOADALL((s + 1) * 32);

        short8v ah[4], al[4], bh[4], bl[4];
#pragma unroll
        for (int f = 0; f < 4; ++f) {
            const int ra = (wr * 64 + f * 16 + lr) * 40 + lc16;
            const int rb = (wc * 64 + f * 16 + lr) * 40 + lc16;
            ah[f] = *(const short8v*)(&sm[SM_AH + ra]);
            al[f] = *(const short8v*)(&sm[SM_AL + ra]);
            bh[f] = *(const short8v*)(&sm[SM_BH + rb]);
            bl[f] = *(const short8v*)(&sm[SM_BL + rb]);
        }
#pragma unroll
        for (int fm = 0; fm < 4; ++fm)
#pragma unroll
            for (int fn = 0; fn < 4; ++fn) {
                acc[fm][fn] = __builtin_amdgcn_mfma_f32_16x16x32_bf16(ah[fm], bh[fn], acc[fm][fn], 0, 0, 0);
                acc[fm][fn] = __builtin_amdgcn_mfma_f32_16x16x32_bf16(ah[fm], bl[fn], acc[fm][fn], 0, 0, 0);
                acc[fm][fn] = __builtin_amdgcn_mfma_f32_16x16x32_bf16(al[fm], bh[fn], acc[fm][fn], 0, 0, 0);
            }
    }
#undef LOADALL

    // epilogue: v = 1.5*A - 0.5*acc (+optional scale/ssqrt); write upper tile
#pragma unroll
    for (int fm = 0; fm < 4; ++fm) {
#pragma unroll
        for (int j = 0; j < 4; ++j) {
            const int row = m0 + wr * 64 + fm * 16 + (l >> 4) * 4 + j;
            const unsigned short* arow = A + (size_t)row * 512;
            const size_t crow = (size_t)row * 512;
#pragma unroll
            for (int fn = 0; fn < 4; ++fn) {
                const int col = n0 + wc * 64 + fn * 16 + lr;
                float pv = bf16_to_f(arow[col]) + bf16_to_f(arow[PLANE + col]);
                if (mode & MODE_SPV) pv *= rn;
                float v = 1.5f * pv - 0.5f * acc[fm][fn][j];
                if (mode & MODE_SQ) v = sgn_sqrt(v * sq);
                acc[fm][fn][j] = v;
                unsigned short hh = bf16_rne(v);
                C[crow + col] = hh;
                C[crow + col + PLANE] = bf16_rne(v - bf16_to_f(hh));
            }
        }
    }

    // mirrored (lower-triangle) tile via LDS transpose, off-diagonal only
    if (ti != tj) {
        const int TP = 132;
        unsigned short* smT = sm;
        const int cst = wc * 64 + lr;
        const int rst = wr * 64 + (l >> 4) * 4;
        const int rc = t >> 1;
        const int rh = (t & 1) * 64;
        __syncthreads();
#pragma unroll
        for (int pl = 0; pl < 2; ++pl) {
#pragma unroll
            for (int fm = 0; fm < 4; ++fm) {
#pragma unroll
                for (int fn = 0; fn < 4; ++fn) {
                    ushort4 q;
                    {
                        float v0 = acc[fm][fn][0], v1 = acc[fm][fn][1];
                        float v2 = acc[fm][fn][2], v3 = acc[fm][fn][3];
                        unsigned short h0 = bf16_rne(v0), h1 = bf16_rne(v1);
                        unsigned short h2 = bf16_rne(v2), h3 = bf16_rne(v3);
                        if (pl == 0) { q.x = h0; q.y = h1; q.z = h2; q.w = h3; }
                        else {
                            q.x = bf16_rne(v0 - bf16_to_f(h0));
                            q.y = bf16_rne(v1 - bf16_to_f(h1));
                            q.z = bf16_rne(v2 - bf16_to_f(h2));
                            q.w = bf16_rne(v3 - bf16_to_f(h3));
                        }
                    }
                    *(ushort4*)&smT[(cst + fn * 16) * TP + rst + fm * 16] = q;
                }
            }
            __syncthreads();
            {
                unsigned short* dst = C + (size_t)(n0 + rc) * 512 + m0 + rh + (pl ? PLANE : 0);
                const unsigned short* srcp = &smT[rc * TP + rh];
#pragma unroll
                for (int k = 0; k < 16; ++k)
                    *(ushort4*)(dst + k * 4) = *(const ushort4*)(srcp + k * 4);
            }
            __syncthreads();
        }
    }
}

// ---------------------------------------------------------------------------
// Gram with in-staging fp32 -> trunc hi/lo pair conversion (xconv fused).
// C_pair = (X X^T)/784 per batch; symmetric 10-tile + mirror; K=784 (25 steps,
// last half-masked). grid 640.
// ---------------------------------------------------------------------------
__global__ __launch_bounds__(256) void gram_direct(const float* __restrict__ X,
                                                   unsigned short* __restrict__ C0,
                                                   float alpha)
{
    __shared__ unsigned short sm[4 * 128 * 40];
    const int SM_AH = 0, SM_AL = 5120, SM_BH = 10240, SM_BL = 15360;

    const int nwg = gridDim.x;
    const int chunk = nwg >> 3;
    const int wu = (blockIdx.x & 7) * chunk + (blockIdx.x >> 3);
    const int bz = wu / 10, tile = wu - bz * 10;
    int ti, tj;
    if (tile < 4)      { ti = 0; tj = tile; }
    else if (tile < 7) { ti = 1; tj = tile - 3; }
    else if (tile < 9) { ti = 2; tj = tile - 5; }
    else               { ti = 3; tj = 3; }
    const int m0 = ti * 128, n0 = tj * 128;
    unsigned short* C = C0 + (size_t)bz * SLOT_USH;

    const int t = threadIdx.x;
    const int l = t & 63;
    const int w = t >> 6;
    const int wr = w >> 1, wc = w & 1;
    const int lr = l & 15, lc16 = (l >> 4) * 8;
    const int sr = t >> 1, sh = t & 1;

    const float* pXa = X + ((size_t)bz * 512 + m0 + sr) * 784 + sh * 16;
    const float* pXb = X + ((size_t)bz * 512 + n0 + sr) * 784 + sh * 16;
    unsigned short* dAh = &sm[SM_AH + sr * 40 + sh * 16];
    unsigned short* dAl = &sm[SM_AL + sr * 40 + sh * 16];
    unsigned short* dBh = &sm[SM_BH + sr * 40 + sh * 16];
    unsigned short* dBl = &sm[SM_BL + sr * 40 + sh * 16];

    f32x4 acc[4][4] = {};

    float4 xa0, xa1, xa2, xa3, xb0, xb1, xb2, xb3;
#define GLD(OFF) do { \
    if ((OFF) + sh * 16 < 784) { \
        xa0 = *(const float4*)(pXa + (OFF));      xa1 = *(const float4*)(pXa + (OFF) + 4); \
        xa2 = *(const float4*)(pXa + (OFF) + 8);  xa3 = *(const float4*)(pXa + (OFF) + 12); \
        xb0 = *(const float4*)(pXb + (OFF));      xb1 = *(const float4*)(pXb + (OFF) + 4); \
        xb2 = *(const float4*)(pXb + (OFF) + 8);  xb3 = *(const float4*)(pXb + (OFF) + 12); \
    } else { \
        xa0 = xa1 = xa2 = xa3 = make_float4(0.f, 0.f, 0.f, 0.f); \
        xb0 = xb1 = xb2 = xb3 = make_float4(0.f, 0.f, 0.f, 0.f); \
    } } while (0)

#define CW(F4, DH, DL, Q) do { \
    ushort4 h4, l4; \
    unsigned ux = __builtin_bit_cast(unsigned, (F4).x); \
    unsigned uy = __builtin_bit_cast(unsigned, (F4).y); \
    unsigned uz = __builtin_bit_cast(unsigned, (F4).z); \
    unsigned uw = __builtin_bit_cast(unsigned, (F4).w); \
    h4.x = (unsigned short)(ux >> 16); h4.y = (unsigned short)(uy >> 16); \
    h4.z = (unsigned short)(uz >> 16); h4.w = (unsigned short)(uw >> 16); \
    l4.x = (unsigned short)(__builtin_bit_cast(unsigned, (F4).x - __builtin_bit_cast(float, ux & 0xFFFF0000u)) >> 16); \
    l4.y = (unsigned short)(__builtin_bit_cast(unsigned, (F4).y - __builtin_bit_cast(float, uy & 0xFFFF0000u)) >> 16); \
    l4.z = (unsigned short)(__builtin_bit_cast(unsigned, (F4).z - __builtin_bit_cast(float, uz & 0xFFFF0000u)) >> 16); \
    l4.w = (unsigned short)(__builtin_bit_cast(unsigned, (F4).w - __builtin_bit_cast(float, uw & 0xFFFF0000u)) >> 16); \
    *(ushort4*)((DH) + (Q) * 4) = h4; \
    *(ushort4*)((DL) + (Q) * 4) = l4; \
  } while (0)

    GLD(0);
    for (int s = 0; s < 25; ++s) {
        __syncthreads();
        CW(xa0, dAh, dAl, 0); CW(xa1, dAh, dAl, 1); CW(xa2, dAh, dAl, 2); CW(xa3, dAh, dAl, 3);
        CW(xb0, dBh, dBl, 0); CW(xb1, dBh, dBl, 1); CW(xb2, dBh, dBl, 2); CW(xb3, dBh, dBl, 3);
        __syncthreads();
        if (s + 1 < 25) GLD((s + 1) * 32);

        short8v ah[4], al[4], bh[4], bl[4];
#pragma unroll
        for (int f = 0; f < 4; ++f) {
            const int ra = (wr * 64 + f * 16 + lr) * 40 + lc16;
            const int rb = (wc * 64 + f * 16 + lr) * 40 + lc16;
            ah[f] = *(const short8v*)(&sm[SM_AH + ra]);
            al[f] = *(const short8v*)(&sm[SM_AL + ra]);
            bh[f] = *(const short8v*)(&sm[SM_BH + rb]);
            bl[f] = *(const short8v*)(&sm[SM_BL + rb]);
        }
#pragma unroll
        for (int fm = 0; fm < 4; ++fm)
#pragma unroll
            for (int fn = 0; fn < 4; ++fn) {
                acc[fm][fn] = __builtin_amdgcn_mfma_f32_16x16x32_bf16(ah[fm], bh[fn], acc[fm][fn], 0, 0, 0);
                acc[fm][fn] = __builtin_amdgcn_mfma_f32_16x16x32_bf16(ah[fm], bl[fn], acc[fm][fn], 0, 0, 0);
                acc[fm][fn] = __builtin_amdgcn_mfma_f32_16x16x32_bf16(al[fm], bh[fn], acc[fm][fn], 0, 0, 0);
            }
    }
#undef GLD
#undef CW

#pragma unroll
    for (int fm = 0; fm < 4; ++fm) {
#pragma unroll
        for (int j = 0; j < 4; ++j) {
            const int row = m0 + wr * 64 + fm * 16 + (l >> 4) * 4 + j;
            const size_t crow = (size_t)row * 512;
#pragma unroll
            for (int fn = 0; fn < 4; ++fn) {
                const int col = n0 + wc * 64 + fn * 16 + lr;
                float v = acc[fm][fn][j] * alpha;
                acc[fm][fn][j] = v;
                unsigned short hh = bf16_rne(v);
                C[crow + col] = hh;
                C[crow + col + PLANE] = bf16_rne(v - bf16_to_f(hh));
            }
        }
    }

    if (ti != tj) {
        const int TP = 132;
        unsigned short* smT = sm;
        const int cst = wc * 64 + lr;
        const int rst = wr * 64 + (l >> 4) * 4;
        const int rc = t >> 1;
        const int rh = (t & 1) * 64;
        __syncthreads();
#pragma unroll
        for (int pl = 0; pl < 2; ++pl) {
#pragma unroll
            for (int fm = 0; fm < 4; ++fm) {
#pragma unroll
                for (int fn = 0; fn < 4; ++fn) {
                    ushort4 q;
                    {
                        float v0 = acc[fm][fn][0], v1 = acc[fm][fn][1];
                        float v2 = acc[fm][fn][2], v3 = acc[fm][fn][3];
                        unsigned short h0 = bf16_rne(v0), h1 = bf16_rne(v1);
                        unsigned short h2 = bf16_rne(v2), h3 = bf16_rne(v3);
                        if (pl == 0) { q.x = h0; q.y = h1; q.z = h2; q.w = h3; }
                        else {
                            q.x = bf16_rne(v0 - bf16_to_f(h0));
                            q.y = bf16_rne(v1 - bf16_to_f(h1));
                            q.z = bf16_rne(v2 - bf16_to_f(h2));
                            q.w = bf16_rne(v3 - bf16_to_f(h3));
                        }
                    }
                    *(ushort4*)&smT[(cst + fn * 16) * TP + rst + fm * 16] = q;
                }
            }
            __syncthreads();
            {
                unsigned short* dst = C + (size_t)(n0 + rc) * 512 + m0 + rh + (pl ? PLANE : 0);
                const unsigned short* srcp = &smT[rc * TP + rh];
#pragma unroll
                for (int k = 0; k < 16; ++k)
                    *(ushort4*)(dst + k * 4) = *(const ushort4*)(srcp + k * 4);
            }
            __syncthreads();
        }
    }
}

// ---------------------------------------------------------------------------
// Frobenius norm, two-stage (latency-friendly): 512-block partial + finish
// ---------------------------------------------------------------------------
__global__ __launch_bounds__(256) void frob_part(const unsigned short* __restrict__ P,
                                                 float* __restrict__ pp)
{
    const int b = blockIdx.x >> 3, sg = blockIdx.x & 7;
    const unsigned short* p = P + (size_t)b * SLOT_USH + sg * 32768;
    float s = 0.f;
    for (int i = threadIdx.x * 8; i < 32768; i += 2048) {
        ushort8v h = *(const ushort8v*)(p + i);
        ushort8v lo = *(const ushort8v*)(p + i + PLANE);
#pragma unroll
        for (int j = 0; j < 8; ++j) {
            float v = bf16_to_f(h[j]) + bf16_to_f(lo[j]);
            s += v * v;
        }
    }
    __shared__ float red[256];
    red[threadIdx.x] = s;
    __syncthreads();
    for (int wd = 128; wd > 0; wd >>= 1) {
        if (threadIdx.x < wd) red[threadIdx.x] += red[threadIdx.x + wd];
        __syncthreads();
    }
    if (threadIdx.x == 0) pp[blockIdx.x] = red[0];
}

__global__ __launch_bounds__(64) void frob_fin(const float* __restrict__ pp,
                                               float* __restrict__ out)
{
    const int b = threadIdx.x;
    float s = 0.f;
#pragma unroll
    for (int i = 0; i < 8; ++i) s += pp[b * 8 + i];
    out[b] = sqrtf(s);
}

// ---------------------------------------------------------------------------
// FC via MFMA, k-split (unchanged from round 4)
// ---------------------------------------------------------------------------
__global__ __launch_bounds__(256) void fc_mfma(
    const unsigned short* __restrict__ Vp, const float* __restrict__ Wfc,
    float* __restrict__ part)
{
    __shared__ unsigned short sm2[15360];
    const int AH = 0, AL = 2560, BH = 5120, BL = 10240;

    const int sp = blockIdx.x >> 1;
    const int nt = blockIdx.x & 1;
    const int kbase = sp * 2048;
    const int n0 = nt * 128;

    const int t = threadIdx.x;
    const int l = t & 63;
    const int w = t >> 6;
    const int wr = w >> 1, wc = w & 1;
    const int lr = l & 15, lc16 = (l >> 4) * 8;

    const int sr = t >> 1, sh = t & 1;
    const unsigned short* gA = Vp + (size_t)sr * SLOT_USH + kbase + sh * 16;
    const int wrow = n0 + sr;
    const bool wv = wrow < 200;
    const float* gB = Wfc + (size_t)wrow * 262144 + kbase + sh * 16;

    unsigned short* dAh = &sm2[AH + sr * 40 + sh * 16];
    unsigned short* dAl = &sm2[AL + sr * 40 + sh * 16];
    unsigned short* dBh = &sm2[BH + sr * 40 + sh * 16];
    unsigned short* dBl = &sm2[BL + sr * 40 + sh * 16];

    f32x4 acc[2][4] = {};

    ushort8v va0, va1, vl0, vl1;
    float4 wf0, wf1, wf2, wf3;
#define FLOAD(OFF) do { \
    if (t < 128) { \
        va0 = *(const ushort8v*)(gA + (OFF));         va1 = *(const ushort8v*)(gA + (OFF) + 8); \
        vl0 = *(const ushort8v*)(gA + PLANE + (OFF)); vl1 = *(const ushort8v*)(gA + PLANE + (OFF) + 8); \
    } \
    if (wv) { \
        wf0 = *(const float4*)(gB + (OFF));      wf1 = *(const float4*)(gB + (OFF) + 4); \
        wf2 = *(const float4*)(gB + (OFF) + 8);  wf3 = *(const float4*)(gB + (OFF) + 12); \
    } else { \
        wf0 = wf1 = wf2 = wf3 = make_float4(0.f, 0.f, 0.f, 0.f); \
    } \
  } while (0)

#define WCONV(F4, Q) do { \
    ushort4 h4, l4; \
    unsigned ux = __builtin_bit_cast(unsigned, (F4).x); \
    unsigned uy = __builtin_bit_cast(unsigned, (F4).y); \
    unsigned uz = __builtin_bit_cast(unsigned, (F4).z); \
    unsigned uw = __builtin_bit_cast(unsigned, (F4).w); \
    h4.x = (unsigned short)(ux >> 16); h4.y = (unsigned short)(uy >> 16); \
    h4.z = (unsigned short)(uz >> 16); h4.w = (unsigned short)(uw >> 16); \
    l4.x = (unsigned short)(__builtin_bit_cast(unsigned, (F4).x - __builtin_bit_cast(float, ux & 0xFFFF0000u)) >> 16); \
    l4.y = (unsigned short)(__builtin_bit_cast(unsigned, (F4).y - __builtin_bit_cast(float, uy & 0xFFFF0000u)) >> 16); \
    l4.z = (unsigned short)(__builtin_bit_cast(unsigned, (F4).z - __builtin_bit_cast(float, uz & 0xFFFF0000u)) >> 16); \
    l4.w = (unsigned short)(__builtin_bit_cast(unsigned, (F4).w - __builtin_bit_cast(float, uw & 0xFFFF0000u)) >> 16); \
    *(ushort4*)(dBh + (Q) * 4) = h4; \
    *(ushort4*)(dBl + (Q) * 4) = l4; \
  } while (0)

    FLOAD(0);
    for (int s = 0; s < 64; ++s) {
        __syncthreads();
        if (t < 128) {
            *(ushort8v*)(dAh) = va0; *(ushort8v*)(dAh + 8) = va1;
            *(ushort8v*)(dAl) = vl0; *(ushort8v*)(dAl + 8) = vl1;
        }
        WCONV(wf0, 0); WCONV(wf1, 1); WCONV(wf2, 2); WCONV(wf3, 3);
        __syncthreads();
        if (s + 1 < 64) FLOAD((s + 1) * 32);

        short8v ah[2], al2[2], bh[4], bl[4];
#pragma unroll
        for (int f = 0; f < 2; ++f) {
            const int ra = (wr * 32 + f * 16 + lr) * 40 + lc16;
            ah[f]  = *(const short8v*)(&sm2[AH + ra]);
            al2[f] = *(const short8v*)(&sm2[AL + ra]);
        }
#pragma unroll
        for (int f = 0; f < 4; ++f) {
            const int rb = (wc * 64 + f * 16 + lr) * 40 + lc16;
            bh[f] = *(const short8v*)(&sm2[BH + rb]);
            bl[f] = *(const short8v*)(&sm2[BL + rb]);
        }
#pragma unroll
        for (int fm = 0; fm < 2; ++fm)
#pragma unroll
            for (int fn = 0; fn < 4; ++fn) {
                acc[fm][fn] = __builtin_amdgcn_mfma_f32_16x16x32_bf16(ah[fm],  bh[fn], acc[fm][fn], 0, 0, 0);
                acc[fm][fn] = __builtin_amdgcn_mfma_f32_16x16x32_bf16(ah[fm],  bl[fn], acc[fm][fn], 0, 0, 0);
                acc[fm][fn] = __builtin_amdgcn_mfma_f32_16x16x32_bf16(al2[fm], bh[fn], acc[fm][fn], 0, 0, 0);
            }
    }
#undef FLOAD
#undef WCONV

    float* pb = part + (size_t)(sp * 2 + nt) * 64 * 128;
#pragma unroll
    for (int fm = 0; fm < 2; ++fm)
#pragma unroll
        for (int j = 0; j < 4; ++j) {
            const int row = wr * 32 + fm * 16 + (l >> 4) * 4 + j;
#pragma unroll
            for (int fn = 0; fn < 4; ++fn) {
                const int col = wc * 64 + fn * 16 + lr;
                pb[(size_t)row * 128 + col] = acc[fm][fn][j];
            }
        }
}

__global__ __launch_bounds__(256) void fc_reduce(
    const float* __restrict__ part, const float* __restrict__ n2,
    const float* __restrict__ bias, float* __restrict__ out)
{
    const int p = blockIdx.x * 256 + threadIdx.x;
    if (p >= 64 * 200) return;
    const int b = p / 200, o = p % 200;
    const int nt = o >> 7, n = o & 127;
    float s = 0.f;
    for (int c = 0; c < 128; ++c)
        s += part[((size_t)(c * 2 + nt) * 64 + b) * 128 + n];
    const float nb = fmaxf(n2[b], 1e-12f);
    out[p] = s / nb + bias[o];
}

// ---------------------------------------------------------------------------
extern "C" void kernel_launch(void* const* d_in, const int* in_sizes, int n_in,
                              void* d_out, int out_size, void* d_ws, size_t ws_size,
                              hipStream_t stream)
{
    const float* X    = (const float*)d_in[0];
    const float* Wfc  = (const float*)d_in[1];
    const float* bias = (const float*)d_in[2];
    float* out = (float*)d_out;

    float* norm  = (float*)d_ws;
    float* norm2 = norm + 64;
    float* fpart = norm2 + 64;                       // 512
    float* part  = fpart + 512;                      // 8 MiB
    unsigned short* region = (unsigned short*)(part + (size_t)256 * 64 * 128);

    unsigned short* P[4];
    for (int i = 0; i < 4; ++i) P[i] = region + (size_t)i * 64 * SLOT_USH;

    // A = X X^T / 784 (conversion fused into staging) -> P0; norm
    gram_direct<<<640, 256, 0, stream>>>(X, P[0], 1.0f / 784.0f);
    frob_part<<<512, 256, 0, stream>>>(P[0], fpart);
    frob_fin<<<1, 64, 0, stream>>>(fpart, norm);

    // --- pipelined NS: 2 batch-groups of 32, offset by one stage ---
    // stage ids: 0=it0a(Y1), 1=it0b(M1), 2..17: (even=s1[U,Ynew], odd=s2[Mnew]),
    // 18=it9+ssqrt -> Vp (slot P3 for both groups by rotation)
    int st[2][4] = {{1, 2, 3, 0}, {1, 2, 3, 0}};    // y, m, f0, f1 slot idx
    for (int tL = 0; tL <= 19; ++tL) {
        NsArgs a = {};
        int ns = 0;
        for (int g = 0; g < 2; ++g) {
            const int sid = (g == 0) ? tL : tL - 1;
            if (sid < 0 || sid > 18) continue;
            const size_t H = (size_t)g * 32 * SLOT_USH;
            const int gb0 = 32 * g;
            int* S = st[g];
            if (sid == 0) {
                a.A[ns] = P[0] + H; a.B[ns] = P[0] + H; a.C[ns] = P[S[0]] + H;
                a.mode[ns] = MODE_SA | MODE_SB | MODE_SPV; a.gb0[ns] = gb0; a.cnt[ns] = 320; ns++;
            } else if (sid == 1) {
                a.A[ns] = P[S[0]] + H; a.B[ns] = P[0] + H; a.C[ns] = P[S[1]] + H;
                a.mode[ns] = MODE_SB; a.gb0[ns] = gb0; a.cnt[ns] = 320; ns++;
            } else if (sid == 18) {
                a.A[ns] = P[S[0]] + H; a.B[ns] = P[S[1]] + H; a.C[ns] = P[S[2]] + H;  // = P3
                a.mode[ns] = MODE_SQ; a.gb0[ns] = gb0; a.cnt[ns] = 320; ns++;
            } else if ((sid & 1) == 0) {            // s1: U = M*T(M); Ynew = Y*T(M)
                a.A[ns] = P[S[1]] + H; a.B[ns] = P[S[1]] + H; a.C[ns] = P[S[2]] + H;
                a.mode[ns] = 0; a.gb0[ns] = gb0; a.cnt[ns] = 320; ns++;
                a.A[ns] = P[S[0]] + H; a.B[ns] = P[S[1]] + H; a.C[ns] = P[S[3]] + H;
                a.mode[ns] = 0; a.gb0[ns] = gb0; a.cnt[ns] = 320; ns++;
            } else {                                // s2: Mnew = U*T(M) -> old Y slot
                a.A[ns] = P[S[2]] + H; a.B[ns] = P[S[1]] + H; a.C[ns] = P[S[0]] + H;
                a.mode[ns] = 0; a.gb0[ns] = gb0; a.cnt[ns] = 320; ns++;
                const int y = S[0], m = S[1], f0 = S[2], f1 = S[3];
                S[0] = f1; S[1] = y; S[2] = f0; S[3] = m;
            }
        }
        if (ns == 0) continue;
        ns_multi<<<dim3(ns * 320), 256, 0, stream>>>(a, norm);
    }

    // Vp = P3 (both groups). n2 = ||v||; FC head
    unsigned short* Vp = P[3];
    frob_part<<<512, 256, 0, stream>>>(Vp, fpart);
    frob_fin<<<1, 64, 0, stream>>>(fpart, norm2);
    fc_mfma<<<dim3(256), 256, 0, stream>>>(Vp, Wfc, part);
    fc_reduce<<<50, 256, 0, stream>>>(part, norm2, bias, out);
}

// Round 6
// 2045.871 us; speedup vs baseline: 1.0842x; 1.0842x over previous
//
#include <hip/hip_runtime.h>
#include <math.h>
#include <stdint.h>

#define DIMM 512
#define MATF ((size_t)DIMM * DIMM)       // 262144
#define PLANE 262144                     // hi -> lo plane offset (ushorts)
#define SLOT_USH (2 * 262144)            // pair slot per batch (ushorts) = 1 MiB

typedef __attribute__((ext_vector_type(8))) short short8v;
typedef __attribute__((ext_vector_type(8))) unsigned short ushort8v;
typedef __attribute__((ext_vector_type(4))) float f32x4;

#define MODE_SQ 1

__device__ __forceinline__ unsigned short bf16_rne(float f) {
    unsigned u = __builtin_bit_cast(unsigned, f);
    u += 0x7FFFu + ((u >> 16) & 1u);
    return (unsigned short)(u >> 16);
}
__device__ __forceinline__ float bf16_to_f(unsigned short h) {
    unsigned u = ((unsigned)h) << 16;
    return __builtin_bit_cast(float, u);
}
__device__ __forceinline__ float sgn_sqrt(float tv)
{
    float r = sqrtf(fabsf(tv) + 1e-5f);
    return tv > 0.f ? r : (tv < 0.f ? -r : 0.f);
}

// width-16 global -> LDS direct copy (dest = uniform base + lane*16)
#define GLOAD16(gp, lp) __builtin_amdgcn_global_load_lds( \
    (const __attribute__((address_space(1))) unsigned int*)(const void*)(gp), \
    (__attribute__((address_space(3))) unsigned int*)(void*)(lp), 16, 0, 0)

// ---------------------------------------------------------------------------
// NS GEMM with global_load_lds staging. C_pair = f(1.5*A - 0.5*(A @ B^T-cols)),
// symmetric 10-tile + LDS-transpose mirror, XCD-aware remap, K=512.
// LDS: 4 planes x 128 rows x 32 ushorts (64B rows, linear). Swizzle: 16B chunk
// cp in LDS holds global chunk cp ^ ((row>>1)&3); applied on global SOURCE at
// staging and on ds_read address (both-sides involution, rule 21).
// mode MODE_SQ: epilogue v = sgn_sqrt(v * sqrt(norm[bz]))   (it9 fusion)
// ---------------------------------------------------------------------------
__global__ __launch_bounds__(256) void ns_gemm(
    const unsigned short* __restrict__ A0, const unsigned short* __restrict__ A1,
    const unsigned short* __restrict__ Bb,
    unsigned short* __restrict__ C0, unsigned short* __restrict__ C1,
    int mode, const float* __restrict__ norm, int nz)
{
    __shared__ __align__(16) unsigned short sm[16896];  // staging 16384 ush; transpose 128x132

    const int nwg = gridDim.x;
    const int chunk = nwg >> 3;                   // nwg % 8 == 0
    const int wu0 = (blockIdx.x & 7) * chunk + (blockIdx.x >> 3);
    const int per_batch = nz * 10;
    const int bz = wu0 / per_batch;
    const int rr2 = wu0 - bz * per_batch;
    const int z  = rr2 / 10;
    const int tile = rr2 - z * 10;
    int ti, tj;
    if (tile < 4)      { ti = 0; tj = tile; }
    else if (tile < 7) { ti = 1; tj = tile - 3; }
    else if (tile < 9) { ti = 2; tj = tile - 5; }
    else               { ti = 3; tj = 3; }

    const unsigned short* A  = (z ? A1 : A0) + (size_t)bz * SLOT_USH;
    const unsigned short* Bp = Bb + (size_t)bz * SLOT_USH;
    unsigned short* C = (z ? C1 : C0) + (size_t)bz * SLOT_USH;

    float sq = 0.f;
    if (mode) sq = sqrtf(norm[bz]);

    const int m0 = ti * 128;
    const int n0 = tj * 128;

    const int t = threadIdx.x;
    const int l = t & 63;
    const int w = t >> 6;
    const int wr = w >> 1, wc = w & 1;
    const int lr = l & 15;
    // swizzled k-chunk offset for fragment reads (lane-constant, ushorts)
    const int sc = (((l >> 4) ^ ((l >> 1) & 3)) << 3);

    // ---- staging setup: wave w stages plane w (0=AH,1=AL,2=BH,3=BL)
    const unsigned short* gplane = (w < 2 ? A : Bp) + ((w & 1) ? PLANE : 0);
    const int rowoff = (w < 2 ? m0 : n0);
    const int rloc = l >> 2;                       // row within 16-row group
    const int cpos = l & 3;                        // LDS chunk position
    const int csrc = cpos ^ ((rloc >> 1) & 3);     // global chunk (pre-swizzled)
    const unsigned short* gp0 = gplane + (size_t)(rowoff + rloc) * 512 + csrc * 8;
    unsigned short* lbase = &sm[w * 4096];

    f32x4 acc[4][4] = {};

    for (int s = 0; s < 16; ++s) {
        __syncthreads();                           // buffer free (prev reads done)
#pragma unroll
        for (int i = 0; i < 8; ++i)
            GLOAD16(gp0 + (size_t)i * 16 * 512 + s * 32, lbase + i * 512);
        __syncthreads();                           // implicit vmcnt(0) drain

        short8v ah[4], al[4], bh[4], bl[4];
#pragma unroll
        for (int f = 0; f < 4; ++f) {
            const int ra = ((wr * 64 + f * 16 + lr) << 5) + sc;
            const int rb = ((wc * 64 + f * 16 + lr) << 5) + sc;
            ah[f] = *(const short8v*)(&sm[ra]);
            al[f] = *(const short8v*)(&sm[4096 + ra]);
            bh[f] = *(const short8v*)(&sm[8192 + rb]);
            bl[f] = *(const short8v*)(&sm[12288 + rb]);
        }
#pragma unroll
        for (int fm = 0; fm < 4; ++fm)
#pragma unroll
            for (int fn = 0; fn < 4; ++fn) {
                acc[fm][fn] = __builtin_amdgcn_mfma_f32_16x16x32_bf16(ah[fm], bh[fn], acc[fm][fn], 0, 0, 0);
                acc[fm][fn] = __builtin_amdgcn_mfma_f32_16x16x32_bf16(ah[fm], bl[fn], acc[fm][fn], 0, 0, 0);
                acc[fm][fn] = __builtin_amdgcn_mfma_f32_16x16x32_bf16(al[fm], bh[fn], acc[fm][fn], 0, 0, 0);
            }
    }

    // epilogue: v = 1.5*A - 0.5*acc (+optional ssqrt); write upper tile
#pragma unroll
    for (int fm = 0; fm < 4; ++fm) {
#pragma unroll
        for (int j = 0; j < 4; ++j) {
            const int row = m0 + wr * 64 + fm * 16 + (l >> 4) * 4 + j;
            const unsigned short* arow = A + (size_t)row * 512;
            const size_t crow = (size_t)row * 512;
#pragma unroll
            for (int fn = 0; fn < 4; ++fn) {
                const int col = n0 + wc * 64 + fn * 16 + lr;
                float pv = bf16_to_f(arow[col]) + bf16_to_f(arow[PLANE + col]);
                float v = 1.5f * pv - 0.5f * acc[fm][fn][j];
                if (mode & MODE_SQ) v = sgn_sqrt(v * sq);
                acc[fm][fn][j] = v;
                unsigned short hh = bf16_rne(v);
                C[crow + col] = hh;
                C[crow + col + PLANE] = bf16_rne(v - bf16_to_f(hh));
            }
        }
    }

    // mirrored (lower-triangle) tile via LDS transpose, off-diagonal only
    if (ti != tj) {
        const int TP = 132;
        unsigned short* smT = sm;
        const int cst = wc * 64 + lr;
        const int rst = wr * 64 + (l >> 4) * 4;
        const int rc = t >> 1;
        const int rh = (t & 1) * 64;
        __syncthreads();
#pragma unroll
        for (int pl = 0; pl < 2; ++pl) {
#pragma unroll
            for (int fm = 0; fm < 4; ++fm) {
#pragma unroll
                for (int fn = 0; fn < 4; ++fn) {
                    ushort4 q;
                    {
                        float v0 = acc[fm][fn][0], v1 = acc[fm][fn][1];
                        float v2 = acc[fm][fn][2], v3 = acc[fm][fn][3];
                        unsigned short h0 = bf16_rne(v0), h1 = bf16_rne(v1);
                        unsigned short h2 = bf16_rne(v2), h3 = bf16_rne(v3);
                        if (pl == 0) { q.x = h0; q.y = h1; q.z = h2; q.w = h3; }
                        else {
                            q.x = bf16_rne(v0 - bf16_to_f(h0));
                            q.y = bf16_rne(v1 - bf16_to_f(h1));
                            q.z = bf16_rne(v2 - bf16_to_f(h2));
                            q.w = bf16_rne(v3 - bf16_to_f(h3));
                        }
                    }
                    *(ushort4*)&smT[(cst + fn * 16) * TP + rst + fm * 16] = q;
                }
            }
            __syncthreads();
            {
                unsigned short* dst = C + (size_t)(n0 + rc) * 512 + m0 + rh + (pl ? PLANE : 0);
                const unsigned short* srcp = &smT[rc * TP + rh];
#pragma unroll
                for (int k = 0; k < 16; ++k)
                    *(ushort4*)(dst + k * 4) = *(const ushort4*)(srcp + k * 4);
            }
            __syncthreads();
        }
    }
}

// ---------------------------------------------------------------------------
// Gram with in-staging fp32 -> trunc hi/lo pair conversion.
// C_pair = (X X^T)/784 per batch; symmetric 10-tile + mirror; K=784.
// ---------------------------------------------------------------------------
__global__ __launch_bounds__(256) void gram_direct(const float* __restrict__ X,
                                                   unsigned short* __restrict__ C0,
                                                   float alpha)
{
    __shared__ unsigned short sm[4 * 128 * 40];
    const int SM_AH = 0, SM_AL = 5120, SM_BH = 10240, SM_BL = 15360;

    const int nwg = gridDim.x;
    const int chunk = nwg >> 3;
    const int wu = (blockIdx.x & 7) * chunk + (blockIdx.x >> 3);
    const int bz = wu / 10, tile = wu - bz * 10;
    int ti, tj;
    if (tile < 4)      { ti = 0; tj = tile; }
    else if (tile < 7) { ti = 1; tj = tile - 3; }
    else if (tile < 9) { ti = 2; tj = tile - 5; }
    else               { ti = 3; tj = 3; }
    const int m0 = ti * 128, n0 = tj * 128;
    unsigned short* C = C0 + (size_t)bz * SLOT_USH;

    const int t = threadIdx.x;
    const int l = t & 63;
    const int w = t >> 6;
    const int wr = w >> 1, wc = w & 1;
    const int lr = l & 15, lc16 = (l >> 4) * 8;
    const int sr = t >> 1, sh = t & 1;

    const float* pXa = X + ((size_t)bz * 512 + m0 + sr) * 784 + sh * 16;
    const float* pXb = X + ((size_t)bz * 512 + n0 + sr) * 784 + sh * 16;
    unsigned short* dAh = &sm[SM_AH + sr * 40 + sh * 16];
    unsigned short* dAl = &sm[SM_AL + sr * 40 + sh * 16];
    unsigned short* dBh = &sm[SM_BH + sr * 40 + sh * 16];
    unsigned short* dBl = &sm[SM_BL + sr * 40 + sh * 16];

    f32x4 acc[4][4] = {};

    float4 xa0, xa1, xa2, xa3, xb0, xb1, xb2, xb3;
#define GLD(OFF) do { \
    if ((OFF) + sh * 16 < 784) { \
        xa0 = *(const float4*)(pXa + (OFF));      xa1 = *(const float4*)(pXa + (OFF) + 4); \
        xa2 = *(const float4*)(pXa + (OFF) + 8);  xa3 = *(const float4*)(pXa + (OFF) + 12); \
        xb0 = *(const float4*)(pXb + (OFF));      xb1 = *(const float4*)(pXb + (OFF) + 4); \
        xb2 = *(const float4*)(pXb + (OFF) + 8);  xb3 = *(const float4*)(pXb + (OFF) + 12); \
    } else { \
        xa0 = xa1 = xa2 = xa3 = make_float4(0.f, 0.f, 0.f, 0.f); \
        xb0 = xb1 = xb2 = xb3 = make_float4(0.f, 0.f, 0.f, 0.f); \
    } } while (0)

#define CW(F4, DH, DL, Q) do { \
    ushort4 h4, l4; \
    unsigned ux = __builtin_bit_cast(unsigned, (F4).x); \
    unsigned uy = __builtin_bit_cast(unsigned, (F4).y); \
    unsigned uz = __builtin_bit_cast(unsigned, (F4).z); \
    unsigned uw = __builtin_bit_cast(unsigned, (F4).w); \
    h4.x = (unsigned short)(ux >> 16); h4.y = (unsigned short)(uy >> 16); \
    h4.z = (unsigned short)(uz >> 16); h4.w = (unsigned short)(uw >> 16); \
    l4.x = (unsigned short)(__builtin_bit_cast(unsigned, (F4).x - __builtin_bit_cast(float, ux & 0xFFFF0000u)) >> 16); \
    l4.y = (unsigned short)(__builtin_bit_cast(unsigned, (F4).y - __builtin_bit_cast(float, uy & 0xFFFF0000u)) >> 16); \
    l4.z = (unsigned short)(__builtin_bit_cast(unsigned, (F4).z - __builtin_bit_cast(float, uz & 0xFFFF0000u)) >> 16); \
    l4.w = (unsigned short)(__builtin_bit_cast(unsigned, (F4).w - __builtin_bit_cast(float, uw & 0xFFFF0000u)) >> 16); \
    *(ushort4*)((DH) + (Q) * 4) = h4; \
    *(ushort4*)((DL) + (Q) * 4) = l4; \
  } while (0)

    GLD(0);
    for (int s = 0; s < 25; ++s) {
        __syncthreads();
        CW(xa0, dAh, dAl, 0); CW(xa1, dAh, dAl, 1); CW(xa2, dAh, dAl, 2); CW(xa3, dAh, dAl, 3);
        CW(xb0, dBh, dBl, 0); CW(xb1, dBh, dBl, 1); CW(xb2, dBh, dBl, 2); CW(xb3, dBh, dBl, 3);
        __syncthreads();
        if (s + 1 < 25) GLD((s + 1) * 32);

        short8v ah[4], al[4], bh[4], bl[4];
#pragma unroll
        for (int f = 0; f < 4; ++f) {
            const int ra = (wr * 64 + f * 16 + lr) * 40 + lc16;
            const int rb = (wc * 64 + f * 16 + lr) * 40 + lc16;
            ah[f] = *(const short8v*)(&sm[SM_AH + ra]);
            al[f] = *(const short8v*)(&sm[SM_AL + ra]);
            bh[f] = *(const short8v*)(&sm[SM_BH + rb]);
            bl[f] = *(const short8v*)(&sm[SM_BL + rb]);
        }
#pragma unroll
        for (int fm = 0; fm < 4; ++fm)
#pragma unroll
            for (int fn = 0; fn < 4; ++fn) {
                acc[fm][fn] = __builtin_amdgcn_mfma_f32_16x16x32_bf16(ah[fm], bh[fn], acc[fm][fn], 0, 0, 0);
                acc[fm][fn] = __builtin_amdgcn_mfma_f32_16x16x32_bf16(ah[fm], bl[fn], acc[fm][fn], 0, 0, 0);
                acc[fm][fn] = __builtin_amdgcn_mfma_f32_16x16x32_bf16(al[fm], bh[fn], acc[fm][fn], 0, 0, 0);
            }
    }
#undef GLD
#undef CW

#pragma unroll
    for (int fm = 0; fm < 4; ++fm) {
#pragma unroll
        for (int j = 0; j < 4; ++j) {
            const int row = m0 + wr * 64 + fm * 16 + (l >> 4) * 4 + j;
            const size_t crow = (size_t)row * 512;
#pragma unroll
            for (int fn = 0; fn < 4; ++fn) {
                const int col = n0 + wc * 64 + fn * 16 + lr;
                float v = acc[fm][fn][j] * alpha;
                acc[fm][fn][j] = v;
                unsigned short hh = bf16_rne(v);
                C[crow + col] = hh;
                C[crow + col + PLANE] = bf16_rne(v - bf16_to_f(hh));
            }
        }
    }

    if (ti != tj) {
        const int TP = 132;
        unsigned short* smT = sm;
        const int cst = wc * 64 + lr;
        const int rst = wr * 64 + (l >> 4) * 4;
        const int rc = t >> 1;
        const int rh = (t & 1) * 64;
        __syncthreads();
#pragma unroll
        for (int pl = 0; pl < 2; ++pl) {
#pragma unroll
            for (int fm = 0; fm < 4; ++fm) {
#pragma unroll
                for (int fn = 0; fn < 4; ++fn) {
                    ushort4 q;
                    {
                        float v0 = acc[fm][fn][0], v1 = acc[fm][fn][1];
                        float v2 = acc[fm][fn][2], v3 = acc[fm][fn][3];
                        unsigned short h0 = bf16_rne(v0), h1 = bf16_rne(v1);
                        unsigned short h2 = bf16_rne(v2), h3 = bf16_rne(v3);
                        if (pl == 0) { q.x = h0; q.y = h1; q.z = h2; q.w = h3; }
                        else {
                            q.x = bf16_rne(v0 - bf16_to_f(h0));
                            q.y = bf16_rne(v1 - bf16_to_f(h1));
                            q.z = bf16_rne(v2 - bf16_to_f(h2));
                            q.w = bf16_rne(v3 - bf16_to_f(h3));
                        }
                    }
                    *(ushort4*)&smT[(cst + fn * 16) * TP + rst + fm * 16] = q;
                }
            }
            __syncthreads();
            {
                unsigned short* dst = C + (size_t)(n0 + rc) * 512 + m0 + rh + (pl ? PLANE : 0);
                const unsigned short* srcp = &smT[rc * TP + rh];
#pragma unroll
                for (int k = 0; k < 16; ++k)
                    *(ushort4*)(dst + k * 4) = *(const ushort4*)(srcp + k * 4);
            }
            __syncthreads();
        }
    }
}

// ---------------------------------------------------------------------------
// Y0_pair = A_pair / norm[b]
// ---------------------------------------------------------------------------
__global__ __launch_bounds__(256) void init_pair(const unsigned short* __restrict__ A,
                                                 unsigned short* __restrict__ Y,
                                                 const float* __restrict__ norm)
{
    const int total = 64 * 32768;
    for (int g = blockIdx.x * 256 + threadIdx.x; g < total; g += gridDim.x * 256) {
        const int b = g >> 15;
        const int off = (g & 32767) * 8;
        const float rn = 1.0f / norm[b];
        const unsigned short* ah = A + (size_t)b * SLOT_USH + off;
        ushort8v h = *(const ushort8v*)ah;
        ushort8v lo = *(const ushort8v*)(ah + PLANE);
        ushort8v oh, ol;
#pragma unroll
        for (int j = 0; j < 8; ++j) {
            float v = (bf16_to_f(h[j]) + bf16_to_f(lo[j])) * rn;
            unsigned short hh = bf16_rne(v);
            oh[j] = hh;
            ol[j] = bf16_rne(v - bf16_to_f(hh));
        }
        unsigned short* y = Y + (size_t)b * SLOT_USH + off;
        *(ushort8v*)y = oh;
        *(ushort8v*)(y + PLANE) = ol;
    }
}

// ---------------------------------------------------------------------------
// Frobenius norm, two-stage: 512-block partial + finish
// ---------------------------------------------------------------------------
__global__ __launch_bounds__(256) void frob_part(const unsigned short* __restrict__ P,
                                                 float* __restrict__ pp)
{
    const int b = blockIdx.x >> 3, sg = blockIdx.x & 7;
    const unsigned short* p = P + (size_t)b * SLOT_USH + sg * 32768;
    float s = 0.f;
    for (int i = threadIdx.x * 8; i < 32768; i += 2048) {
        ushort8v h = *(const ushort8v*)(p + i);
        ushort8v lo = *(const ushort8v*)(p + i + PLANE);
#pragma unroll
        for (int j = 0; j < 8; ++j) {
            float v = bf16_to_f(h[j]) + bf16_to_f(lo[j]);
            s += v * v;
        }
    }
    __shared__ float red[256];
    red[threadIdx.x] = s;
    __syncthreads();
    for (int wd = 128; wd > 0; wd >>= 1) {
        if (threadIdx.x < wd) red[threadIdx.x] += red[threadIdx.x + wd];
        __syncthreads();
    }
    if (threadIdx.x == 0) pp[blockIdx.x] = red[0];
}

__global__ __launch_bounds__(64) void frob_fin(const float* __restrict__ pp,
                                               float* __restrict__ out)
{
    const int b = threadIdx.x;
    float s = 0.f;
#pragma unroll
    for (int i = 0; i < 8; ++i) s += pp[b * 8 + i];
    out[b] = sqrtf(s);
}

// ---------------------------------------------------------------------------
// FC via MFMA, k-split: grid 256 (128 sp x 2 nt)
// ---------------------------------------------------------------------------
__global__ __launch_bounds__(256) void fc_mfma(
    const unsigned short* __restrict__ Vp, const float* __restrict__ Wfc,
    float* __restrict__ part)
{
    __shared__ unsigned short sm2[15360];
    const int AH = 0, AL = 2560, BH = 5120, BL = 10240;

    const int sp = blockIdx.x >> 1;
    const int nt = blockIdx.x & 1;
    const int kbase = sp * 2048;
    const int n0 = nt * 128;

    const int t = threadIdx.x;
    const int l = t & 63;
    const int w = t >> 6;
    const int wr = w >> 1, wc = w & 1;
    const int lr = l & 15, lc16 = (l >> 4) * 8;

    const int sr = t >> 1, sh = t & 1;
    const unsigned short* gA = Vp + (size_t)sr * SLOT_USH + kbase + sh * 16;
    const int wrow = n0 + sr;
    const bool wv = wrow < 200;
    const float* gB = Wfc + (size_t)wrow * 262144 + kbase + sh * 16;

    unsigned short* dAh = &sm2[AH + sr * 40 + sh * 16];
    unsigned short* dAl = &sm2[AL + sr * 40 + sh * 16];
    unsigned short* dBh = &sm2[BH + sr * 40 + sh * 16];
    unsigned short* dBl = &sm2[BL + sr * 40 + sh * 16];

    f32x4 acc[2][4] = {};

    ushort8v va0, va1, vl0, vl1;
    float4 wf0, wf1, wf2, wf3;
#define FLOAD(OFF) do { \
    if (t < 128) { \
        va0 = *(const ushort8v*)(gA + (OFF));         va1 = *(const ushort8v*)(gA + (OFF) + 8); \
        vl0 = *(const ushort8v*)(gA + PLANE + (OFF)); vl1 = *(const ushort8v*)(gA + PLANE + (OFF) + 8); \
    } \
    if (wv) { \
        wf0 = *(const float4*)(gB + (OFF));      wf1 = *(const float4*)(gB + (OFF) + 4); \
        wf2 = *(const float4*)(gB + (OFF) + 8);  wf3 = *(const float4*)(gB + (OFF) + 12); \
    } else { \
        wf0 = wf1 = wf2 = wf3 = make_float4(0.f, 0.f, 0.f, 0.f); \
    } \
  } while (0)

#define WCONV(F4, Q) do { \
    ushort4 h4, l4; \
    unsigned ux = __builtin_bit_cast(unsigned, (F4).x); \
    unsigned uy = __builtin_bit_cast(unsigned, (F4).y); \
    unsigned uz = __builtin_bit_cast(unsigned, (F4).z); \
    unsigned uw = __builtin_bit_cast(unsigned, (F4).w); \
    h4.x = (unsigned short)(ux >> 16); h4.y = (unsigned short)(uy >> 16); \
    h4.z = (unsigned short)(uz >> 16); h4.w = (unsigned short)(uw >> 16); \
    l4.x = (unsigned short)(__builtin_bit_cast(unsigned, (F4).x - __builtin_bit_cast(float, ux & 0xFFFF0000u)) >> 16); \
    l4.y = (unsigned short)(__builtin_bit_cast(unsigned, (F4).y - __builtin_bit_cast(float, uy & 0xFFFF0000u)) >> 16); \
    l4.z = (unsigned short)(__builtin_bit_cast(unsigned, (F4).z - __builtin_bit_cast(float, uz & 0xFFFF0000u)) >> 16); \
    l4.w = (unsigned short)(__builtin_bit_cast(unsigned, (F4).w - __builtin_bit_cast(float, uw & 0xFFFF0000u)) >> 16); \
    *(ushort4*)(dBh + (Q) * 4) = h4; \
    *(ushort4*)(dBl + (Q) * 4) = l4; \
  } while (0)

    FLOAD(0);
    for (int s = 0; s < 64; ++s) {
        __syncthreads();
        if (t < 128) {
            *(ushort8v*)(dAh) = va0; *(ushort8v*)(dAh + 8) = va1;
            *(ushort8v*)(dAl) = vl0; *(ushort8v*)(dAl + 8) = vl1;
        }
        WCONV(wf0, 0); WCONV(wf1, 1); WCONV(wf2, 2); WCONV(wf3, 3);
        __syncthreads();
        if (s + 1 < 64) FLOAD((s + 1) * 32);

        short8v ah[2], al2[2], bh[4], bl[4];
#pragma unroll
        for (int f = 0; f < 2; ++f) {
            const int ra = (wr * 32 + f * 16 + lr) * 40 + lc16;
            ah[f]  = *(const short8v*)(&sm2[AH + ra]);
            al2[f] = *(const short8v*)(&sm2[AL + ra]);
        }
#pragma unroll
        for (int f = 0; f < 4; ++f) {
            const int rb = (wc * 64 + f * 16 + lr) * 40 + lc16;
            bh[f] = *(const short8v*)(&sm2[BH + rb]);
            bl[f] = *(const short8v*)(&sm2[BL + rb]);
        }
#pragma unroll
        for (int fm = 0; fm < 2; ++fm)
#pragma unroll
            for (int fn = 0; fn < 4; ++fn) {
                acc[fm][fn] = __builtin_amdgcn_mfma_f32_16x16x32_bf16(ah[fm],  bh[fn], acc[fm][fn], 0, 0, 0);
                acc[fm][fn] = __builtin_amdgcn_mfma_f32_16x16x32_bf16(ah[fm],  bl[fn], acc[fm][fn], 0, 0, 0);
                acc[fm][fn] = __builtin_amdgcn_mfma_f32_16x16x32_bf16(al2[fm], bh[fn], acc[fm][fn], 0, 0, 0);
            }
    }
#undef FLOAD
#undef WCONV

    float* pb = part + (size_t)(sp * 2 + nt) * 64 * 128;
#pragma unroll
    for (int fm = 0; fm < 2; ++fm)
#pragma unroll
        for (int j = 0; j < 4; ++j) {
            const int row = wr * 32 + fm * 16 + (l >> 4) * 4 + j;
#pragma unroll
            for (int fn = 0; fn < 4; ++fn) {
                const int col = wc * 64 + fn * 16 + lr;
                pb[(size_t)row * 128 + col] = acc[fm][fn][j];
            }
        }
}

__global__ __launch_bounds__(256) void fc_reduce(
    const float* __restrict__ part, const float* __restrict__ n2,
    const float* __restrict__ bias, float* __restrict__ out)
{
    const int p = blockIdx.x * 256 + threadIdx.x;
    if (p >= 64 * 200) return;
    const int b = p / 200, o = p % 200;
    const int nt = o >> 7, n = o & 127;
    float s = 0.f;
    for (int c = 0; c < 128; ++c)
        s += part[((size_t)(c * 2 + nt) * 64 + b) * 128 + n];
    const float nb = fmaxf(n2[b], 1e-12f);
    out[p] = s / nb + bias[o];
}

// ---------------------------------------------------------------------------
extern "C" void kernel_launch(void* const* d_in, const int* in_sizes, int n_in,
                              void* d_out, int out_size, void* d_ws, size_t ws_size,
                              hipStream_t stream)
{
    const float* X    = (const float*)d_in[0];
    const float* Wfc  = (const float*)d_in[1];
    const float* bias = (const float*)d_in[2];
    float* out = (float*)d_out;

    float* norm  = (float*)d_ws;
    float* norm2 = norm + 64;
    float* fpart = norm2 + 64;                       // 512
    float* part  = fpart + 512;                      // 8 MiB
    unsigned short* region = (unsigned short*)(part + (size_t)256 * 64 * 128);

    unsigned short* P[4];
    for (int i = 0; i < 4; ++i) P[i] = region + (size_t)i * 64 * SLOT_USH;

    // A = X X^T / 784 -> P0; norm; Y0 = A/norm -> P1
    gram_direct<<<640, 256, 0, stream>>>(X, P[0], 1.0f / 784.0f);
    frob_part<<<512, 256, 0, stream>>>(P[0], fpart);
    frob_fin<<<1, 64, 0, stream>>>(fpart, norm);
    init_pair<<<1024, 256, 0, stream>>>(P[0], P[1], norm);

    // Newton-Schulz (M-form): T(M) = (3I - M)/2 folded into epilogue
    // it0a: Y1 = Y0*T(Y0) -> P2 ; it0b: M1 = Y1*T(Y0) -> P3
    ns_gemm<<<640, 256, 0, stream>>>(P[1], P[1], P[1], P[2], P[2], 0, norm, 1);
    ns_gemm<<<640, 256, 0, stream>>>(P[2], P[2], P[1], P[3], P[3], 0, norm, 1);

    unsigned short *Y = P[2], *M = P[3], *F0 = P[0], *F1 = P[1];
    for (int it = 1; it <= 8; ++it) {
        // s1 merged: z=0: U = M*T(M) -> F0 ; z=1: Ynew = Y*T(M) -> F1
        ns_gemm<<<1280, 256, 0, stream>>>(M, Y, M, F0, F1, 0, norm, 2);
        // s2: Mnew = U*T(M) -> old Y slot
        ns_gemm<<<640, 256, 0, stream>>>(F0, F0, M, Y, Y, 0, norm, 1);
        unsigned short* Mold = M;
        M = Y;        // Mnew in old Y slot
        Y = F1;       // Ynew
        F1 = Mold;    // Mold freed; F0 unchanged
    }
    // it9 + fused signed-sqrt: V = sgnsqrt( (Y*T(M)) * sqrt(norm) ) -> F0 (=P0)
    ns_gemm<<<640, 256, 0, stream>>>(Y, Y, M, F0, F0, MODE_SQ, norm, 1);

    unsigned short* Vp = F0;
    frob_part<<<512, 256, 0, stream>>>(Vp, fpart);
    frob_fin<<<1, 64, 0, stream>>>(fpart, norm2);
    fc_mfma<<<dim3(256), 256, 0, stream>>>(Vp, Wfc, part);
    fc_reduce<<<50, 256, 0, stream>>>(part, norm2, bias, out);
}